// Round 18
// baseline (120.913 us; speedup 1.0000x reference)
//
#include <hip/hip_runtime.h>

// ConvCaps (Matrix Capsules w/ EM routing), MI355X fp32 implementation.
// One block per output position (b, oi, oj): 784 blocks x 256 threads.
//
// v12 = v11 with POSE READS MOVED OFF THE DS PIPE. v11's post-mortem:
// +5.5% but VALUBusy pinned at 44% -> wrong pipe. DS audit: 4 ds_read_b128
// (pose) + swizzle + sA per chunk/wave ~60cy; x 12.25 waves/CU = ~735cy DS
// demand per ~960cy chunk-round = 77% DS-pipe utilization (DS is per-CU,
// shared by 4 SIMDs) -> heavy bursty queuing = the unhidden stall.
// Fix: delete sP; poses read directly from global x (each half-wave's pose
// row is a 64B all-lanes-broadcast -> 1 L1/L2 cache-line request). Pose
// working set 9KB/block (L1-resident), x 4.2MB (L2/L3-resident). DS/chunk
// 60 -> ~12cy (swizzle + sA). Cost: ~8 int ops/chunk addr calc (VALU idle).
// prA/prB one-chunk-ahead prefetch kept; shifted softmax (v10) kept;
// single vote + single wr buffer kept (VGPR 120, under the 128 cliff).

namespace {

constexpr int OHW  = 14;
constexpr int NPOS = 4 * OHW * OHW;     // 784
constexpr int NN   = 144;               // K*K*B = 3*3*16
constexpr int CC   = 32;
constexpr float LAMB  = 0.01f;
constexpr float EPSF  = 1e-6f;
constexpr float LN2PI = 1.8378770664093453f;
constexpr int NSUB = 8;                 // n-slices: 4 waves x 2 halves
constexpr int NCH  = NN / NSUB;         // 18 chunks per pass (even)
constexpr int RST  = 36;                // sRed/sStat row stride (floats)

// DPP cross-lane move within rows of 16 (VALU, no DS). CTRL: row_ror:N = 0x120|N.
template <int CTRL>
__device__ __forceinline__ float dpp_mov(float x) {
  union { float f; int i; } u, r;
  u.f = x;
  r.i = __builtin_amdgcn_update_dpp(0, u.i, CTRL, 0xF, 0xF, true);
  return r.f;
}

// lane ^ 16 within each 32-lane group (one DS op). BitMode offset = (16<<10)|0x1F.
__device__ __forceinline__ float swz_xor16(float x) {
  union { float f; int i; } u, r;
  u.f = x;
  r.i = __builtin_amdgcn_ds_swizzle(u.i, 0x401F);
  return r.f;
}

__device__ __forceinline__ void mat44(const float4 pr[4], const float4 wr[4], float v[16]) {
  #pragma unroll
  for (int i = 0; i < 4; ++i) {
    v[4*i+0] = fmaf(pr[i].x, wr[0].x, fmaf(pr[i].y, wr[1].x, fmaf(pr[i].z, wr[2].x, pr[i].w * wr[3].x)));
    v[4*i+1] = fmaf(pr[i].x, wr[0].y, fmaf(pr[i].y, wr[1].y, fmaf(pr[i].z, wr[2].y, pr[i].w * wr[3].y)));
    v[4*i+2] = fmaf(pr[i].x, wr[0].z, fmaf(pr[i].y, wr[1].z, fmaf(pr[i].z, wr[2].z, pr[i].w * wr[3].z)));
    v[4*i+3] = fmaf(pr[i].x, wr[0].w, fmaf(pr[i].y, wr[1].w, fmaf(pr[i].z, wr[2].w, pr[i].w * wr[3].w)));
  }
}

__device__ __forceinline__ void loadw(float4 wr[4], const float* __restrict__ w, int n, int c) {
  const float4* W = (const float4*)(w + n * 512 + c * 16);
  wr[0] = W[0]; wr[1] = W[1]; wr[2] = W[2]; wr[3] = W[3];
}

// pose row n of this block's patch, straight from global x (broadcast read).
// n = (kh*3+kw)*16 + bc; offset = kh*4096 + kw*256 + bc*16 from xbase.
__device__ __forceinline__ void loadp_g(float4 pr[4], const float* __restrict__ xbase, int n) {
  const int m  = n >> 4;            // 0..8
  const int kh = m / 3;             // compiler magic-mul
  const int kw = m - 3 * kh;
  const int bc = n & 15;
  const float4* Pp = (const float4*)(xbase + kh * 4096 + kw * 256 + bc * 16);
  pr[0] = Pp[0]; pr[1] = Pp[1]; pr[2] = Pp[2]; pr[3] = Pp[3];
}

// shifted softmax over 32 classes (xv<=0 by construction) + unnormalized M-acc
__device__ __forceinline__ void fuse_chunk(const float v[16], float an,
                                           const float hi[16], const float hm[16],
                                           float kcp,
                                           float& T0, float T1[16], float T2[16]) {
  float s0 = 0.f, s1 = 0.f, s2 = 0.f, s3 = 0.f;
  #pragma unroll
  for (int p = 0; p < 4; ++p) {
    s0 = fmaf(fmaf(hi[p],      v[p],      hm[p]),      v[p],      s0);
    s1 = fmaf(fmaf(hi[p + 4],  v[p + 4],  hm[p + 4]),  v[p + 4],  s1);
    s2 = fmaf(fmaf(hi[p + 8],  v[p + 8],  hm[p + 8]),  v[p + 8],  s2);
    s3 = fmaf(fmaf(hi[p + 12], v[p + 12], hm[p + 12]), v[p + 12], s3);
  }
  const float xv = kcp - ((s0 + s1) + (s2 + s3));
  const float e = __expf(xv);
  float z = e;
  z += dpp_mov<0x128>(z);
  z += dpp_mov<0x124>(z);
  z += dpp_mov<0x122>(z);
  z += dpp_mov<0x121>(z);
  z += swz_xor16(z);
  const float rn = an * e * __builtin_amdgcn_rcpf(z);
  T0 += rn;
  #pragma unroll
  for (int p = 0; p < 16; ++p) {
    const float rv = rn * v[p];
    T1[p] += rv;
    T2[p] = fmaf(rv, v[p], T2[p]);
  }
}

__global__ __launch_bounds__(256)
void convcaps_em(const float* __restrict__ x,
                 const float* __restrict__ a,
                 const float* __restrict__ w,        // (144, 32, 4, 4)
                 const float* __restrict__ beta_u,   // (32,1)
                 const float* __restrict__ beta_a,   // (32,1)
                 const int*   __restrict__ iters_p,
                 float* __restrict__ out_mu,         // (4,14,14,32,16)
                 float* __restrict__ out_a)          // (4,14,14,32,1)
{
  __shared__ float sA[NN];                           // input activations
  __shared__ __align__(16) float sRed[4][CC][RST];   // per-wave partials: [0..15]=S1 [16..31]=S2 [32]=S0
  __shared__ __align__(16) float sStat[CC][RST];     // reduced stats per class

  const int tid = threadIdx.x;
  const int pos = blockIdx.x;
  const int b   = pos / (OHW * OHW);
  const int rem = pos - b * (OHW * OHW);
  const int oi  = rem / OHW;
  const int oj  = rem - oi * OHW;

  int iters = iters_p[0];
  iters = (iters < 1) ? 1 : (iters > 16 ? 16 : iters);

  // base of this block's patch in x: x[b, oi, oj, 0, 0]
  const float* xbase = x + (((b * 16 + oi) * 16) + oj) * 256;

  // ---- stage activations only (poses come from L1/L2 directly) ----
  if (tid < NN) {
    const int kh = tid / 48, kw = (tid >> 4) % 3, bc = tid & 15;
    sA[tid] = a[(((b * 16 + oi + kh) * 16) + (oj + kw)) * 16 + bc];
  }
  __syncthreads();

  // thread map: class in lane bits 0..4; n-slice = wv*2 + (lane>>5).
  const int lane = tid & 63;
  const int wv   = tid >> 6;
  const int c    = lane & 31;
  const int half = lane >> 5;
  const int sub  = wv * 2 + half;           // 0..7
  const float bu16 = 16.0f * beta_u[c];
  const float ba   = beta_a[c];

  float mu[16], hi[16], hm[16];
  float kcp = 0.f, aout = 0.f;

  for (int it = 0; it < iters; ++it) {
    float T0 = 0.f, T1[16], T2[16];
    #pragma unroll
    for (int p = 0; p < 16; ++p) { T1[p] = 0.f; T2[p] = 0.f; }

    float4 prA[4], prB[4], wr[4];
    loadw(wr, w, sub, c);
    loadp_g(prA, xbase, sub);

    if (it == 0) {
      // ---- M0: r ~ a_in (unnormalized), no softmax; prefetched loads ----
      #pragma unroll 1
      for (int i = 0; i < NCH / 2; ++i) {
        const int n0 = sub + NSUB * (2 * i);
        loadp_g(prB, xbase, n0 + NSUB);     // pose ch 2i+1, in flight over acc
        float v[16];
        mat44(prA, wr, v);
        loadw(wr, w, n0 + NSUB, c);         // weights ch 2i+1, in flight
        {
          const float rn = sA[n0];
          T0 += rn;
          #pragma unroll
          for (int p = 0; p < 16; ++p) {
            const float rv = rn * v[p];
            T1[p] += rv;
            T2[p] = fmaf(rv, v[p], T2[p]);
          }
        }
        if (i < NCH / 2 - 1) loadp_g(prA, xbase, n0 + 2 * NSUB);
        mat44(prB, wr, v);
        if (i < NCH / 2 - 1) loadw(wr, w, n0 + 2 * NSUB, c);
        {
          const float rn = sA[n0 + NSUB];
          T0 += rn;
          #pragma unroll
          for (int p = 0; p < 16; ++p) {
            const float rv = rn * v[p];
            T1[p] += rv;
            T2[p] = fmaf(rv, v[p], T2[p]);
          }
        }
      }
    } else {
      // ---- fused E+M (shifted softmax); prefetched loads ----
      #pragma unroll 1
      for (int i = 0; i < NCH / 2; ++i) {
        const int n0 = sub + NSUB * (2 * i);
        loadp_g(prB, xbase, n0 + NSUB);     // next chunk's pose: hides under fuse
        float v[16];
        mat44(prA, wr, v);
        loadw(wr, w, n0 + NSUB, c);         // next chunk's weights: hides under fuse
        fuse_chunk(v, sA[n0], hi, hm, kcp, T0, T1, T2);
        if (i < NCH / 2 - 1) loadp_g(prA, xbase, n0 + 2 * NSUB);
        mat44(prB, wr, v);
        if (i < NCH / 2 - 1) loadw(wr, w, n0 + 2 * NSUB, c);
        fuse_chunk(v, sA[n0 + NSUB], hi, hm, kcp, T0, T1, T2);
      }
    }

    // ---- combine the two halves of each wave ----
    T0 += __shfl_xor(T0, 32);
    #pragma unroll
    for (int p = 0; p < 16; ++p) {
      T1[p] += __shfl_xor(T1[p], 32);
      T2[p] += __shfl_xor(T2[p], 32);
    }

    // ---- once-per-pass cross-wave reduce (2 barriers) ----
    if (half == 0) {
      float4* d = (float4*)(&sRed[wv][c][0]);
      d[0] = make_float4(T1[0],  T1[1],  T1[2],  T1[3]);
      d[1] = make_float4(T1[4],  T1[5],  T1[6],  T1[7]);
      d[2] = make_float4(T1[8],  T1[9],  T1[10], T1[11]);
      d[3] = make_float4(T1[12], T1[13], T1[14], T1[15]);
      d[4] = make_float4(T2[0],  T2[1],  T2[2],  T2[3]);
      d[5] = make_float4(T2[4],  T2[5],  T2[6],  T2[7]);
      d[6] = make_float4(T2[8],  T2[9],  T2[10], T2[11]);
      d[7] = make_float4(T2[12], T2[13], T2[14], T2[15]);
      sRed[wv][c][32] = T0;
    }
    __syncthreads();
    {
      // 256 threads x 4 slots cover the 32x32 S1/S2 grid; lanes<32 do S0.
      const int c2 = tid & 31;
      const int s2 = tid >> 5;            // 0..7
      const float q0 = sRed[0][c2][s2]      + sRed[1][c2][s2]      + sRed[2][c2][s2]      + sRed[3][c2][s2];
      const float q1 = sRed[0][c2][s2 + 8]  + sRed[1][c2][s2 + 8]  + sRed[2][c2][s2 + 8]  + sRed[3][c2][s2 + 8];
      const float q2 = sRed[0][c2][s2 + 16] + sRed[1][c2][s2 + 16] + sRed[2][c2][s2 + 16] + sRed[3][c2][s2 + 16];
      const float q3 = sRed[0][c2][s2 + 24] + sRed[1][c2][s2 + 24] + sRed[2][c2][s2 + 24] + sRed[3][c2][s2 + 24];
      sStat[c2][s2]      = q0;
      sStat[c2][s2 + 8]  = q1;
      sStat[c2][s2 + 16] = q2;
      sStat[c2][s2 + 24] = q3;
      if (tid < 32)
        sStat[tid][32] = sRed[0][tid][32] + sRed[1][tid][32] + sRed[2][tid][32] + sRed[3][tid][32];
    }
    __syncthreads();

    // ---- per-class stats (redundant across the 8 threads sharing c) ----
    const float4* R = (const float4*)(&sStat[c][0]);
    const float4 u1a = R[0], u1b = R[1], u1c = R[2], u1d = R[3];
    const float4 u2a = R[4], u2b = R[5], u2c = R[6], u2d = R[7];
    const float U0 = sStat[c][32];
    float U1[16] = {u1a.x,u1a.y,u1a.z,u1a.w, u1b.x,u1b.y,u1b.z,u1b.w,
                    u1c.x,u1c.y,u1c.z,u1c.w, u1d.x,u1d.y,u1d.z,u1d.w};
    float U2[16] = {u2a.x,u2a.y,u2a.z,u2a.w, u2b.x,u2b.y,u2b.z,u2b.w,
                    u2c.x,u2c.y,u2c.z,u2c.w, u2d.x,u2d.y,u2d.z,u2d.w};

    // it==0: coeff = a/(sum a + 32*EPS), r_sum = U0/32; else coeff = r/(T0+EPS), r_sum = T0
    const float inv  = 1.0f / (U0 + ((it == 0) ? (CC * EPSF) : EPSF));
    const float rsum = (it == 0) ? U0 * (1.0f / CC) : U0;
    float logsum = 0.f;
    #pragma unroll
    for (int p = 0; p < 16; ++p) {
      const float m = U1[p] * inv;
      mu[p] = m;
      float sig = fmaf(m, fmaf(m, U0, -2.0f * U1[p]), U2[p]) * inv + EPSF;  // sum r(v-mu)^2 * inv + eps
      sig = fmaxf(sig, 1e-12f);
      logsum += __logf(sig);
      hi[p] = 0.5f / sig;
    }
    const float cost = rsum * (bu16 + 0.5f * logsum);
    aout = 1.0f / (1.0f + __expf(-LAMB * (ba - cost)));

    if (it < iters - 1) {
      float K = 0.f;
      #pragma unroll
      for (int p = 0; p < 16; ++p) {
        hm[p] = -2.0f * hi[p] * mu[p];
        K = fmaf(hi[p] * mu[p], mu[p], K);
      }
      const float logA = __logf(aout + EPSF) - 0.5f * logsum - 8.0f * LN2PI;
      // per-pass shift M = max over the 32 classes of logA (exact, once)
      float M = logA;
      M = fmaxf(M, dpp_mov<0x128>(M));
      M = fmaxf(M, dpp_mov<0x124>(M));
      M = fmaxf(M, dpp_mov<0x122>(M));
      M = fmaxf(M, dpp_mov<0x121>(M));
      M = fmaxf(M, swz_xor16(M));
      kcp = (logA - M) - K;               // xv = (logA - M) - q <= 0
    }
  }

  // ---- epilogue: wave 0, half 0 holds every class once ----
  if (tid < 32) {
    float4* om = (float4*)(out_mu + (size_t)pos * 512 + c * 16);
    om[0] = make_float4(mu[0],  mu[1],  mu[2],  mu[3]);
    om[1] = make_float4(mu[4],  mu[5],  mu[6],  mu[7]);
    om[2] = make_float4(mu[8],  mu[9],  mu[10], mu[11]);
    om[3] = make_float4(mu[12], mu[13], mu[14], mu[15]);
    out_a[pos * CC + c] = aout;
  }
}

} // namespace

extern "C" void kernel_launch(void* const* d_in, const int* in_sizes, int n_in,
                              void* d_out, int out_size, void* d_ws, size_t ws_size,
                              hipStream_t stream) {
  const float* x  = (const float*)d_in[0];
  const float* a  = (const float*)d_in[1];
  const float* w  = (const float*)d_in[2];
  const float* bu = (const float*)d_in[3];
  const float* ba = (const float*)d_in[4];
  const int* iters = (const int*)d_in[5];

  float* out_mu = (float*)d_out;                       // 4*14*14*32*16 = 401408
  float* out_a  = out_mu + (size_t)NPOS * CC * 16;     // + 4*14*14*32  =  25088

  convcaps_em<<<NPOS, 256, 0, stream>>>(x, a, w, bu, ba, iters, out_mu, out_a);
}

// Round 19
// 109.349 us; speedup vs baseline: 1.1058x; 1.1058x over previous
//
#include <hip/hip_runtime.h>

// ConvCaps (Matrix Capsules w/ EM routing), MI355X fp32 implementation.
// One block per output position (b, oi, oj): 784 blocks x 256 threads.
//
// v13 = v11 (measured best: 54.4us) + per-wave temporal skew at pass start.
// v12 post-mortem: global pose reads regressed (54.4->67.8, VALUBusy 44->39)
// -> DS-pipe-queuing theory FALSIFIED; LDS pose reads restored.
// Remaining model: VALU issue ~24us (VALUBusy x dur, stable v4-v11); the
// ~30us gap is unhidden chain latency. 3 waves/SIMD x 330cy issue/chunk
// SHOULD hide each ~150cy chain stall -- unless waves are phase-locked in
// OP TYPE: identical-duration chunk bodies after a common barrier keep all
// waves issuing mat44 together, then all stalling on z-allreduce (shared DS
// swizzle + transcendental exp) together. v8's chunk-INDEX stagger changed
// data, not timing -> said nothing about this. Fix: s_sleep(wv) after each
// pass barrier (~64*wv cy skew, max 192cy vs ~6000cy loop) so op phases
// interleave across waves. Zero arithmetic change; single isolated delta.

namespace {

constexpr int OHW  = 14;
constexpr int NPOS = 4 * OHW * OHW;     // 784
constexpr int NN   = 144;               // K*K*B = 3*3*16
constexpr int CC   = 32;
constexpr float LAMB  = 0.01f;
constexpr float EPSF  = 1e-6f;
constexpr float LN2PI = 1.8378770664093453f;
constexpr int NSUB = 8;                 // n-slices: 4 waves x 2 halves
constexpr int NCH  = NN / NSUB;         // 18 chunks per pass (even)
constexpr int RST  = 36;                // sRed/sStat row stride (floats)

// DPP cross-lane move within rows of 16 (VALU, no DS). CTRL: row_ror:N = 0x120|N.
template <int CTRL>
__device__ __forceinline__ float dpp_mov(float x) {
  union { float f; int i; } u, r;
  u.f = x;
  r.i = __builtin_amdgcn_update_dpp(0, u.i, CTRL, 0xF, 0xF, true);
  return r.f;
}

// lane ^ 16 within each 32-lane group (one DS op). BitMode offset = (16<<10)|0x1F.
__device__ __forceinline__ float swz_xor16(float x) {
  union { float f; int i; } u, r;
  u.f = x;
  r.i = __builtin_amdgcn_ds_swizzle(u.i, 0x401F);
  return r.f;
}

__device__ __forceinline__ void mat44(const float4 pr[4], const float4 wr[4], float v[16]) {
  #pragma unroll
  for (int i = 0; i < 4; ++i) {
    v[4*i+0] = fmaf(pr[i].x, wr[0].x, fmaf(pr[i].y, wr[1].x, fmaf(pr[i].z, wr[2].x, pr[i].w * wr[3].x)));
    v[4*i+1] = fmaf(pr[i].x, wr[0].y, fmaf(pr[i].y, wr[1].y, fmaf(pr[i].z, wr[2].y, pr[i].w * wr[3].y)));
    v[4*i+2] = fmaf(pr[i].x, wr[0].z, fmaf(pr[i].y, wr[1].z, fmaf(pr[i].z, wr[2].z, pr[i].w * wr[3].z)));
    v[4*i+3] = fmaf(pr[i].x, wr[0].w, fmaf(pr[i].y, wr[1].w, fmaf(pr[i].z, wr[2].w, pr[i].w * wr[3].w)));
  }
}

__device__ __forceinline__ void loadw(float4 wr[4], const float* __restrict__ w, int n, int c) {
  const float4* W = (const float4*)(w + n * 512 + c * 16);
  wr[0] = W[0]; wr[1] = W[1]; wr[2] = W[2]; wr[3] = W[3];
}

__device__ __forceinline__ void loadp(float4 pr[4], const float* __restrict__ sP, int n) {
  const float4* Pp = (const float4*)(sP + n * 16);
  pr[0] = Pp[0]; pr[1] = Pp[1]; pr[2] = Pp[2]; pr[3] = Pp[3];
}

// shifted softmax over 32 classes (xv<=0 by construction) + unnormalized M-acc
__device__ __forceinline__ void fuse_chunk(const float v[16], float an,
                                           const float hi[16], const float hm[16],
                                           float kcp,
                                           float& T0, float T1[16], float T2[16]) {
  float s0 = 0.f, s1 = 0.f, s2 = 0.f, s3 = 0.f;
  #pragma unroll
  for (int p = 0; p < 4; ++p) {
    s0 = fmaf(fmaf(hi[p],      v[p],      hm[p]),      v[p],      s0);
    s1 = fmaf(fmaf(hi[p + 4],  v[p + 4],  hm[p + 4]),  v[p + 4],  s1);
    s2 = fmaf(fmaf(hi[p + 8],  v[p + 8],  hm[p + 8]),  v[p + 8],  s2);
    s3 = fmaf(fmaf(hi[p + 12], v[p + 12], hm[p + 12]), v[p + 12], s3);
  }
  const float xv = kcp - ((s0 + s1) + (s2 + s3));
  const float e = __expf(xv);
  float z = e;
  z += dpp_mov<0x128>(z);
  z += dpp_mov<0x124>(z);
  z += dpp_mov<0x122>(z);
  z += dpp_mov<0x121>(z);
  z += swz_xor16(z);
  const float rn = an * e * __builtin_amdgcn_rcpf(z);
  T0 += rn;
  #pragma unroll
  for (int p = 0; p < 16; ++p) {
    const float rv = rn * v[p];
    T1[p] += rv;
    T2[p] = fmaf(rv, v[p], T2[p]);
  }
}

__global__ __launch_bounds__(256)
void convcaps_em(const float* __restrict__ x,
                 const float* __restrict__ a,
                 const float* __restrict__ w,        // (144, 32, 4, 4)
                 const float* __restrict__ beta_u,   // (32,1)
                 const float* __restrict__ beta_a,   // (32,1)
                 const int*   __restrict__ iters_p,
                 float* __restrict__ out_mu,         // (4,14,14,32,16)
                 float* __restrict__ out_a)          // (4,14,14,32,1)
{
  __shared__ __align__(16) float sP[NN * 16];        // pose patch (broadcast reads)
  __shared__ float sA[NN];                           // input activations
  __shared__ __align__(16) float sRed[4][CC][RST];   // per-wave partials: [0..15]=S1 [16..31]=S2 [32]=S0
  __shared__ __align__(16) float sStat[CC][RST];     // reduced stats per class

  const int tid = threadIdx.x;
  const int pos = blockIdx.x;
  const int b   = pos / (OHW * OHW);
  const int rem = pos - b * (OHW * OHW);
  const int oi  = rem / OHW;
  const int oj  = rem - oi * OHW;

  int iters = iters_p[0];
  iters = (iters < 1) ? 1 : (iters > 16 ? 16 : iters);

  // ---- stage pose patch + activations ----
  #pragma unroll
  for (int t = 0; t < 9; ++t) {
    const int kh = t / 3, kw = t % 3;
    sP[t * 256 + tid] = x[(((b * 16 + oi + kh) * 16) + (oj + kw)) * 256 + tid];
  }
  if (tid < NN) {
    const int kh = tid / 48, kw = (tid >> 4) % 3, bc = tid & 15;
    sA[tid] = a[(((b * 16 + oi + kh) * 16) + (oj + kw)) * 16 + bc];
  }
  __syncthreads();

  // thread map: class in lane bits 0..4; n-slice = wv*2 + (lane>>5).
  const int lane = tid & 63;
  const int wv   = tid >> 6;
  const int c    = lane & 31;
  const int half = lane >> 5;
  const int sub  = wv * 2 + half;           // 0..7
  const float bu16 = 16.0f * beta_u[c];
  const float ba   = beta_a[c];

  float mu[16], hi[16], hm[16];
  float kcp = 0.f, aout = 0.f;

  for (int it = 0; it < iters; ++it) {
    float T0 = 0.f, T1[16], T2[16];
    #pragma unroll
    for (int p = 0; p < 16; ++p) { T1[p] = 0.f; T2[p] = 0.f; }

    float4 prA[4], prB[4], wr[4];
    loadw(wr, w, sub, c);
    loadp(prA, sP, sub);

    // ---- temporal skew: desynchronize op phases across co-resident waves.
    // wv is wave-uniform -> scalar branch; ~64*wv cycles, max 192 vs ~6000cy loop.
    if (wv == 1)      __builtin_amdgcn_s_sleep(1);
    else if (wv == 2) __builtin_amdgcn_s_sleep(2);
    else if (wv == 3) __builtin_amdgcn_s_sleep(3);

    if (it == 0) {
      // ---- M0: r ~ a_in (unnormalized), no softmax; prefetched loads ----
      #pragma unroll 1
      for (int i = 0; i < NCH / 2; ++i) {
        const int n0 = sub + NSUB * (2 * i);
        loadp(prB, sP, n0 + NSUB);          // pose ch 2i+1, in flight over acc
        float v[16];
        mat44(prA, wr, v);
        loadw(wr, w, n0 + NSUB, c);         // weights ch 2i+1, in flight
        {
          const float rn = sA[n0];
          T0 += rn;
          #pragma unroll
          for (int p = 0; p < 16; ++p) {
            const float rv = rn * v[p];
            T1[p] += rv;
            T2[p] = fmaf(rv, v[p], T2[p]);
          }
        }
        if (i < NCH / 2 - 1) loadp(prA, sP, n0 + 2 * NSUB);
        mat44(prB, wr, v);
        if (i < NCH / 2 - 1) loadw(wr, w, n0 + 2 * NSUB, c);
        {
          const float rn = sA[n0 + NSUB];
          T0 += rn;
          #pragma unroll
          for (int p = 0; p < 16; ++p) {
            const float rv = rn * v[p];
            T1[p] += rv;
            T2[p] = fmaf(rv, v[p], T2[p]);
          }
        }
      }
    } else {
      // ---- fused E+M (shifted softmax); prefetched loads ----
      #pragma unroll 1
      for (int i = 0; i < NCH / 2; ++i) {
        const int n0 = sub + NSUB * (2 * i);
        loadp(prB, sP, n0 + NSUB);          // next chunk's pose: hides under fuse
        float v[16];
        mat44(prA, wr, v);
        loadw(wr, w, n0 + NSUB, c);         // next chunk's weights: hides under fuse
        fuse_chunk(v, sA[n0], hi, hm, kcp, T0, T1, T2);
        if (i < NCH / 2 - 1) loadp(prA, sP, n0 + 2 * NSUB);
        mat44(prB, wr, v);
        if (i < NCH / 2 - 1) loadw(wr, w, n0 + 2 * NSUB, c);
        fuse_chunk(v, sA[n0 + NSUB], hi, hm, kcp, T0, T1, T2);
      }
    }

    // ---- combine the two halves of each wave ----
    T0 += __shfl_xor(T0, 32);
    #pragma unroll
    for (int p = 0; p < 16; ++p) {
      T1[p] += __shfl_xor(T1[p], 32);
      T2[p] += __shfl_xor(T2[p], 32);
    }

    // ---- once-per-pass cross-wave reduce (2 barriers) ----
    if (half == 0) {
      float4* d = (float4*)(&sRed[wv][c][0]);
      d[0] = make_float4(T1[0],  T1[1],  T1[2],  T1[3]);
      d[1] = make_float4(T1[4],  T1[5],  T1[6],  T1[7]);
      d[2] = make_float4(T1[8],  T1[9],  T1[10], T1[11]);
      d[3] = make_float4(T1[12], T1[13], T1[14], T1[15]);
      d[4] = make_float4(T2[0],  T2[1],  T2[2],  T2[3]);
      d[5] = make_float4(T2[4],  T2[5],  T2[6],  T2[7]);
      d[6] = make_float4(T2[8],  T2[9],  T2[10], T2[11]);
      d[7] = make_float4(T2[12], T2[13], T2[14], T2[15]);
      sRed[wv][c][32] = T0;
    }
    __syncthreads();
    {
      // 256 threads x 4 slots cover the 32x32 S1/S2 grid; lanes<32 do S0.
      const int c2 = tid & 31;
      const int s2 = tid >> 5;            // 0..7
      const float q0 = sRed[0][c2][s2]      + sRed[1][c2][s2]      + sRed[2][c2][s2]      + sRed[3][c2][s2];
      const float q1 = sRed[0][c2][s2 + 8]  + sRed[1][c2][s2 + 8]  + sRed[2][c2][s2 + 8]  + sRed[3][c2][s2 + 8];
      const float q2 = sRed[0][c2][s2 + 16] + sRed[1][c2][s2 + 16] + sRed[2][c2][s2 + 16] + sRed[3][c2][s2 + 16];
      const float q3 = sRed[0][c2][s2 + 24] + sRed[1][c2][s2 + 24] + sRed[2][c2][s2 + 24] + sRed[3][c2][s2 + 24];
      sStat[c2][s2]      = q0;
      sStat[c2][s2 + 8]  = q1;
      sStat[c2][s2 + 16] = q2;
      sStat[c2][s2 + 24] = q3;
      if (tid < 32)
        sStat[tid][32] = sRed[0][tid][32] + sRed[1][tid][32] + sRed[2][tid][32] + sRed[3][tid][32];
    }
    __syncthreads();

    // ---- per-class stats (redundant across the 8 threads sharing c) ----
    const float4* R = (const float4*)(&sStat[c][0]);
    const float4 u1a = R[0], u1b = R[1], u1c = R[2], u1d = R[3];
    const float4 u2a = R[4], u2b = R[5], u2c = R[6], u2d = R[7];
    const float U0 = sStat[c][32];
    float U1[16] = {u1a.x,u1a.y,u1a.z,u1a.w, u1b.x,u1b.y,u1b.z,u1b.w,
                    u1c.x,u1c.y,u1c.z,u1c.w, u1d.x,u1d.y,u1d.z,u1d.w};
    float U2[16] = {u2a.x,u2a.y,u2a.z,u2a.w, u2b.x,u2b.y,u2b.z,u2b.w,
                    u2c.x,u2c.y,u2c.z,u2c.w, u2d.x,u2d.y,u2d.z,u2d.w};

    // it==0: coeff = a/(sum a + 32*EPS), r_sum = U0/32; else coeff = r/(T0+EPS), r_sum = T0
    const float inv  = 1.0f / (U0 + ((it == 0) ? (CC * EPSF) : EPSF));
    const float rsum = (it == 0) ? U0 * (1.0f / CC) : U0;
    float logsum = 0.f;
    #pragma unroll
    for (int p = 0; p < 16; ++p) {
      const float m = U1[p] * inv;
      mu[p] = m;
      float sig = fmaf(m, fmaf(m, U0, -2.0f * U1[p]), U2[p]) * inv + EPSF;  // sum r(v-mu)^2 * inv + eps
      sig = fmaxf(sig, 1e-12f);
      logsum += __logf(sig);
      hi[p] = 0.5f / sig;
    }
    const float cost = rsum * (bu16 + 0.5f * logsum);
    aout = 1.0f / (1.0f + __expf(-LAMB * (ba - cost)));

    if (it < iters - 1) {
      float K = 0.f;
      #pragma unroll
      for (int p = 0; p < 16; ++p) {
        hm[p] = -2.0f * hi[p] * mu[p];
        K = fmaf(hi[p] * mu[p], mu[p], K);
      }
      const float logA = __logf(aout + EPSF) - 0.5f * logsum - 8.0f * LN2PI;
      // per-pass shift M = max over the 32 classes of logA (exact, once)
      float M = logA;
      M = fmaxf(M, dpp_mov<0x128>(M));
      M = fmaxf(M, dpp_mov<0x124>(M));
      M = fmaxf(M, dpp_mov<0x122>(M));
      M = fmaxf(M, dpp_mov<0x121>(M));
      M = fmaxf(M, swz_xor16(M));
      kcp = (logA - M) - K;               // xv = (logA - M) - q <= 0
    }
  }

  // ---- epilogue: wave 0, half 0 holds every class once ----
  if (tid < 32) {
    float4* om = (float4*)(out_mu + (size_t)pos * 512 + c * 16);
    om[0] = make_float4(mu[0],  mu[1],  mu[2],  mu[3]);
    om[1] = make_float4(mu[4],  mu[5],  mu[6],  mu[7]);
    om[2] = make_float4(mu[8],  mu[9],  mu[10], mu[11]);
    om[3] = make_float4(mu[12], mu[13], mu[14], mu[15]);
    out_a[pos * CC + c] = aout;
  }
}

} // namespace

extern "C" void kernel_launch(void* const* d_in, const int* in_sizes, int n_in,
                              void* d_out, int out_size, void* d_ws, size_t ws_size,
                              hipStream_t stream) {
  const float* x  = (const float*)d_in[0];
  const float* a  = (const float*)d_in[1];
  const float* w  = (const float*)d_in[2];
  const float* bu = (const float*)d_in[3];
  const float* ba = (const float*)d_in[4];
  const int* iters = (const int*)d_in[5];

  float* out_mu = (float*)d_out;                       // 4*14*14*32*16 = 401408
  float* out_a  = out_mu + (size_t)NPOS * CC * 16;     // + 4*14*14*32  =  25088

  convcaps_em<<<NPOS, 256, 0, stream>>>(x, a, w, bu, ba, iters, out_mu, out_a);
}